// Round 8
// baseline (234.339 us; speedup 1.0000x reference)
//
#include <hip/hip_runtime.h>
#include <cstddef>

#define B_ 4
#define L_ 1024
#define H_ 16
#define DH_ 64
#define HID_ 1024
#define HEADSZ_ 4194304   // B*H*L*DH

typedef short bf16x8 __attribute__((ext_vector_type(8)));
typedef short bf16x4 __attribute__((ext_vector_type(4)));
typedef float f32x4  __attribute__((ext_vector_type(4)));

__device__ __forceinline__ short f2bf(float f) {
    unsigned u = __float_as_uint(f);
    u = (u + 0x7fffu + ((u >> 16) & 1u)) >> 16;   // RNE
    return (short)u;
}
__device__ __forceinline__ float bf2f(short s) {
    return __uint_as_float(((unsigned)(unsigned short)s) << 16);
}
__device__ __forceinline__ void glds16(const short* g, short* l) {
    __builtin_amdgcn_global_load_lds(
        (const __attribute__((address_space(1))) unsigned int*)g,
        (__attribute__((address_space(3))) unsigned int*)l, 16, 0, 0);
}

// ---------------------------------------------------------------------------
// Merged prep: [0,2048) xcast | [2048,3072) wcast4 | [3072,3136) relcast.
// ---------------------------------------------------------------------------
__global__ __launch_bounds__(256) void prep_k(
    const float* __restrict__ x,
    const float* __restrict__ Wq, const float* __restrict__ Wk,
    const float* __restrict__ Wv, const float* __restrict__ Wo,
    const float* __restrict__ rel,
    short* __restrict__ xb, short* __restrict__ Wt, short* __restrict__ relimg)
{
    const int bid = blockIdx.x;
    const int t   = threadIdx.x;
    if (bid < 2048) {                      // x fp32 -> bf16
        const int base = (bid * 256 + t) << 3;
        float4 f0 = *(const float4*)&x[base];
        float4 f1 = *(const float4*)&x[base + 4];
        bf16x8 p;
        p[0] = f2bf(f0.x); p[1] = f2bf(f0.y); p[2] = f2bf(f0.z); p[3] = f2bf(f0.w);
        p[4] = f2bf(f1.x); p[5] = f2bf(f1.y); p[6] = f2bf(f1.z); p[7] = f2bf(f1.w);
        *(bf16x8*)&xb[base] = p;
    } else if (bid < 3072) {               // W transpose+cast: Wt[n][k] = W[k][n]
        const int idx = bid - 2048;
        const int z = idx >> 8, tile = idx & 255;
        const float* W = (z == 0) ? Wq : (z == 1) ? Wk : (z == 2) ? Wv : Wo;
        short* dstb = Wt + (size_t)z * HID_ * HID_;
        __shared__ float T[64][65];
        const int k0 = (tile & 15) << 6, n0 = (tile >> 4) << 6;
        const int r  = t & 63;
        const int cg = t >> 6;
#pragma unroll
        for (int u = 0; u < 4; ++u) {
            float4 f = *(const float4*)&W[(size_t)(k0 + r) * HID_ + n0 + (cg << 4) + (u << 2)];
            T[r][(cg << 4) + (u << 2) + 0] = f.x;
            T[r][(cg << 4) + (u << 2) + 1] = f.y;
            T[r][(cg << 4) + (u << 2) + 2] = f.z;
            T[r][(cg << 4) + (u << 2) + 3] = f.w;
        }
        __syncthreads();
        bf16x8 p0, p1;
#pragma unroll
        for (int j = 0; j < 8; ++j) p0[j] = f2bf(T[(cg << 4) + j][r]);
#pragma unroll
        for (int j = 0; j < 8; ++j) p1[j] = f2bf(T[(cg << 4) + 8 + j][r]);
        short* dst = &dstb[(size_t)(n0 + r) * HID_ + k0 + (cg << 4)];
        *(bf16x8*)dst       = p0;
        *(bf16x8*)(dst + 8) = p1;
    } else {                               // rel -> 32 swizzled 8KB chunk images
        const int base = ((bid - 3072) * 256 + t) << 3;
        if (base >= 2047 * 64) return;
        const int r = base >> 6, d0 = base & 63;
        float4 f0 = *(const float4*)&rel[base];
        float4 f1 = *(const float4*)&rel[base + 4];
        bf16x8 p;
        p[0] = f2bf(f0.x); p[1] = f2bf(f0.y); p[2] = f2bf(f0.z); p[3] = f2bf(f0.w);
        p[4] = f2bf(f1.x); p[5] = f2bf(f1.y); p[6] = f2bf(f1.z); p[7] = f2bf(f1.w);
        const size_t dst = ((size_t)(r >> 6) << 12) + ((r & 63) << 6)
                         + ((((d0 >> 3) ^ (r & 7))) << 3);
        *(bf16x8*)&relimg[dst] = p;
    }
}

// ---------------------------------------------------------------------------
// bf16 MFMA GEMM, 128x128 tile, BK=32 (16 KB LDS), launch_bounds(256,3)
// -> target 3 blocks/CU (m97 operating point). Source-permuted swizzle:
// LDS slot (row,g) holds kgroup g^((row>>1)&3) -> uniform bank spread.
// mode 0: fp32 out (bias b0). mode 1: bf16 qkv (q plain / k image / v image).
// ---------------------------------------------------------------------------
__global__ __launch_bounds__(256, 3) void gemm_glds_k(
    const short* __restrict__ A, const short* __restrict__ Wt,
    const float* __restrict__ b0, const float* __restrict__ b1,
    const float* __restrict__ b2, void* __restrict__ outv,
    int K, int mode)
{
    __shared__ short As[128 * 32];
    __shared__ short Bs[128 * 32];

    const int t    = threadIdx.x;
    const int lane = t & 63, w = t >> 6;
    const int m0   = blockIdx.y << 7, n0 = blockIdx.x << 7;
    const int fr   = lane & 15, qd = lane >> 4;
    const int wm0  = (w & 1) << 6, wn0 = (w >> 1) << 6;

    const int srow = lane >> 2;                      // 0..15 within chunk
    const int sg   = (lane & 3) ^ ((lane >> 3) & 3); // swizzled source kgroup
    const int slot = qd ^ ((fr >> 1) & 3);           // read-side slot group

    f32x4 acc[4][4];
#pragma unroll
    for (int i = 0; i < 4; ++i)
#pragma unroll
        for (int j = 0; j < 4; ++j) acc[i][j] = (f32x4){0.f, 0.f, 0.f, 0.f};

    const short* aBase  = A  + (size_t)(m0 + w * 32 + srow) * K + sg * 8;
    const short* aBase2 = aBase + (size_t)16 * K;
    const short* bBase  = Wt + (size_t)(n0 + w * 32 + srow) * K + sg * 8;
    const short* bBase2 = bBase + (size_t)16 * K;
    short* aDst  = &As[(w * 32) * 32];
    short* aDst2 = &As[(w * 32 + 16) * 32];
    short* bDst  = &Bs[(w * 32) * 32];
    short* bDst2 = &Bs[(w * 32 + 16) * 32];

    for (int k0 = 0; k0 < K; k0 += 32) {
        __syncthreads();
        glds16(aBase + k0, aDst);
        glds16(aBase2 + k0, aDst2);
        glds16(bBase + k0, bDst);
        glds16(bBase2 + k0, bDst2);
        __syncthreads();

        bf16x8 af[4], bfv[4];
#pragma unroll
        for (int mt = 0; mt < 4; ++mt)
            af[mt] = *(const bf16x8*)&As[((wm0 + (mt << 4) + fr) << 5) + (slot << 3)];
#pragma unroll
        for (int nt = 0; nt < 4; ++nt)
            bfv[nt] = *(const bf16x8*)&Bs[((wn0 + (nt << 4) + fr) << 5) + (slot << 3)];
#pragma unroll
        for (int mt = 0; mt < 4; ++mt)
#pragma unroll
            for (int nt = 0; nt < 4; ++nt)
                acc[mt][nt] = __builtin_amdgcn_mfma_f32_16x16x32_bf16(
                    af[mt], bfv[nt], acc[mt][nt], 0, 0, 0);
    }

#pragma unroll
    for (int nt = 0; nt < 4; ++nt) {
        const int coln = n0 + wn0 + (nt << 4) + fr;
        float bias;
        if (mode == 0) bias = b0[coln];
        else {
            const int t3 = coln >> 10;
            bias = (t3 == 0 ? b0 : t3 == 1 ? b1 : b2)[coln & 1023];
        }
#pragma unroll
        for (int mt = 0; mt < 4; ++mt)
#pragma unroll
            for (int rg = 0; rg < 4; ++rg) {
                const int row = m0 + wm0 + (mt << 4) + (qd << 2) + rg;
                const float val = acc[mt][nt][rg] + bias;
                if (mode == 0) {
                    ((float*)outv)[(size_t)row * HID_ + coln] = val;
                } else {
                    const int t3 = coln >> 10;
                    const int h  = (coln >> 6) & 15;
                    const int d  = coln & 63;
                    const int bb = row >> 10, l = row & 1023;
                    const size_t bhoff = ((size_t)(bb * H_ + h)) << 16;
                    size_t dst;
                    if (t3 == 0)        // q: plain [b,h,l,d]
                        dst = bhoff + ((size_t)l << 6) + d;
                    else if (t3 == 1)   // k: swizzled tile image
                        dst = (size_t)HEADSZ_ + bhoff + ((size_t)(l >> 6) << 12)
                            + ((l & 63) << 6) + ((((d >> 3) ^ (l & 7))) << 3) + (d & 7);
                    else                // v: transposed swizzled tile image [d][j=l]
                        dst = 2 * (size_t)HEADSZ_ + bhoff + ((size_t)(l >> 6) << 12)
                            + ((size_t)d << 6) + (((((l >> 3) & 7) ^ (d & 7))) << 3) + (l & 7);
                    ((short*)outv)[dst] = f2bf(val);
                }
            }
    }
}

// ---------------------------------------------------------------------------
// MFMA attention with double-buffered staging: tile jt+1's 6 glds16 issue
// BEFORE tile jt's compute, so the vmcnt(0) drain at the next barrier finds
// the loads already complete. LDS 75776 B -> 2 blocks/CU.
// ---------------------------------------------------------------------------
__global__ __launch_bounds__(256, 2) void attn_mfma_k(
    const short* __restrict__ q, const short* __restrict__ kimg,
    const short* __restrict__ vimg, const short* __restrict__ relimg,
    short* __restrict__ ctx)
{
    __shared__ __align__(16) short Ks[2][64 * 64];
    __shared__ __align__(16) short Vt[2][64 * 64];
    __shared__ __align__(16) short Rl[2][64 * 64];
    __shared__ __align__(16) short Ts[2 * 64 * 68];
    __shared__ __align__(16) short Ps[64 * 72];

    const int t    = threadIdx.x;
    const int i0   = blockIdx.x << 6;
    const int h    = blockIdx.y;
    const int b    = blockIdx.z;
    const size_t bh = (size_t)(b * H_ + h) << 16;
    const int lane = t & 63, w = t >> 6;
    const int fr   = lane & 15, qd = lane >> 4;
    const int m16  = i0 >> 6;
    const int iiB  = (w << 4) + (qd << 2);
    const int soff = w * 1024 + lane * 8;

    bf16x8 af[2];
#pragma unroll
    for (int hh = 0; hh < 2; ++hh)
        af[hh] = *(const bf16x8*)&q[bh + ((size_t)(i0 + (w << 4) + fr) << 6)
                                    + (((hh << 2) + qd) << 3)];

    // prologue: rel chunk m16+16 -> Rl[1]; T into parity m16&1
    glds16(relimg + ((size_t)(m16 + 16) << 12) + soff,       &Rl[1][w * 1024]);
    glds16(relimg + ((size_t)(m16 + 16) << 12) + soff + 512, &Rl[1][w * 1024 + 512]);
    __syncthreads();
    {
        f32x4 acc_t[4];
#pragma unroll
        for (int i = 0; i < 4; ++i) acc_t[i] = (f32x4){0.f, 0.f, 0.f, 0.f};
#pragma unroll
        for (int hh = 0; hh < 2; ++hh) {
            const int g = (hh << 2) + qd;
#pragma unroll
            for (int rt = 0; rt < 4; ++rt) {
                const int rr = (rt << 4) + fr;
                bf16x8 br = *(const bf16x8*)&Rl[1][(rr << 6) + ((g ^ (rr & 7)) << 3)];
                acc_t[rt] = __builtin_amdgcn_mfma_f32_16x16x32_bf16(af[hh], br, acc_t[rt], 0, 0, 0);
            }
        }
        const int pu = m16 & 1;
#pragma unroll
        for (int rt = 0; rt < 4; ++rt) {
            bf16x4 p;
            p[0] = f2bf(acc_t[rt][0]); p[1] = f2bf(acc_t[rt][1]);
            p[2] = f2bf(acc_t[rt][2]); p[3] = f2bf(acc_t[rt][3]);
            *(bf16x4*)&Ts[pu * 4352 + ((rt << 4) + fr) * 68 + iiB] = p;
        }
    }

    // preload tile 0 into buffer 0 (chunk m16+15 -> Rl[0])
    glds16(kimg + bh + soff,        &Ks[0][w * 1024]);
    glds16(kimg + bh + soff + 512,  &Ks[0][w * 1024 + 512]);
    glds16(vimg + bh + soff,        &Vt[0][w * 1024]);
    glds16(vimg + bh + soff + 512,  &Vt[0][w * 1024 + 512]);
    glds16(relimg + ((size_t)(m16 + 15) << 12) + soff,       &Rl[0][w * 1024]);
    glds16(relimg + ((size_t)(m16 + 15) << 12) + soff + 512, &Rl[0][w * 1024 + 512]);

    f32x4 acc_o[4];
#pragma unroll
    for (int i = 0; i < 4; ++i) acc_o[i] = (f32x4){0.f, 0.f, 0.f, 0.f};
    float den[4] = {0.f, 0.f, 0.f, 0.f};

    for (int jt = 0; jt < 16; ++jt) {
        const int cur  = jt & 1, nxt = cur ^ 1;
        const int mlow = m16 + 15 - jt;
        const int pl   = mlow & 1;

        __syncthreads();   // drains this wave's tile-jt glds; nxt buffer free

        if (jt < 15) {     // prefetch tile jt+1 behind this tile's compute
            glds16(kimg + bh + ((size_t)(jt + 1) << 12) + soff,       &Ks[nxt][w * 1024]);
            glds16(kimg + bh + ((size_t)(jt + 1) << 12) + soff + 512, &Ks[nxt][w * 1024 + 512]);
            glds16(vimg + bh + ((size_t)(jt + 1) << 12) + soff,       &Vt[nxt][w * 1024]);
            glds16(vimg + bh + ((size_t)(jt + 1) << 12) + soff + 512, &Vt[nxt][w * 1024 + 512]);
            glds16(relimg + ((size_t)(mlow - 1) << 12) + soff,        &Rl[nxt][w * 1024]);
            glds16(relimg + ((size_t)(mlow - 1) << 12) + soff + 512,  &Rl[nxt][w * 1024 + 512]);
        }

        // S = Q K^T
        f32x4 acc_s[4];
#pragma unroll
        for (int i = 0; i < 4; ++i) acc_s[i] = (f32x4){0.f, 0.f, 0.f, 0.f};
#pragma unroll
        for (int hh = 0; hh < 2; ++hh) {
            const int g = (hh << 2) + qd;
#pragma unroll
            for (int nt = 0; nt < 4; ++nt) {
                const int rb = (nt << 4) + fr;
                bf16x8 bk = *(const bf16x8*)&Ks[cur][(rb << 6) + ((g ^ (rb & 7)) << 3)];
                acc_s[nt] = __builtin_amdgcn_mfma_f32_16x16x32_bf16(af[hh], bk, acc_s[nt], 0, 0, 0);
            }
        }

        // new T chunk (rows 64*mlow .. +63)
        {
            f32x4 acc_t[4];
#pragma unroll
            for (int i = 0; i < 4; ++i) acc_t[i] = (f32x4){0.f, 0.f, 0.f, 0.f};
#pragma unroll
            for (int hh = 0; hh < 2; ++hh) {
                const int g = (hh << 2) + qd;
#pragma unroll
                for (int rt = 0; rt < 4; ++rt) {
                    const int rr = (rt << 4) + fr;
                    bf16x8 br = *(const bf16x8*)&Rl[cur][(rr << 6) + ((g ^ (rr & 7)) << 3)];
                    acc_t[rt] = __builtin_amdgcn_mfma_f32_16x16x32_bf16(af[hh], br, acc_t[rt], 0, 0, 0);
                }
            }
#pragma unroll
            for (int rt = 0; rt < 4; ++rt) {
                bf16x4 p;
                p[0] = f2bf(acc_t[rt][0]); p[1] = f2bf(acc_t[rt][1]);
                p[2] = f2bf(acc_t[rt][2]); p[3] = f2bf(acc_t[rt][3]);
                *(bf16x4*)&Ts[pl * 4352 + ((rt << 4) + fr) * 68 + iiB] = p;
            }
        }
        // Ts/Ps wave-private: lgkm ordering suffices

        // exp + diagonal T gather + P -> LDS
#pragma unroll
        for (int nt = 0; nt < 4; ++nt) {
            const int jj = (nt << 4) + fr;
#pragma unroll
            for (int rg = 0; rg < 4; ++rg) {
                const int ii = iiB + rg;
                const int r7 = ii - jj + 63;
                const int par = pl ^ (r7 >> 6);
                const float tv = bf2f(Ts[par * 4352 + (r7 & 63) * 68 + ii]);
                float s = acc_s[nt][rg] * 0.125f;
                s = fminf(fmaxf(s, -100000.f), 100000.f);
                const float e = __expf(s + tv);
                den[rg] += e;
                Ps[ii * 72 + jj] = f2bf(e);
            }
        }

        // O += P V
#pragma unroll
        for (int hh = 0; hh < 2; ++hh) {
            const int g = (hh << 2) + qd;
            bf16x8 ap = *(const bf16x8*)&Ps[((w << 4) + fr) * 72 + (g << 3)];
#pragma unroll
            for (int nt = 0; nt < 4; ++nt) {
                const int rb = (nt << 4) + fr;
                bf16x8 bv = *(const bf16x8*)&Vt[cur][(rb << 6) + ((g ^ (rb & 7)) << 3)];
                acc_o[nt] = __builtin_amdgcn_mfma_f32_16x16x32_bf16(ap, bv, acc_o[nt], 0, 0, 0);
            }
        }
    }

#pragma unroll
    for (int off = 1; off < 16; off <<= 1)
#pragma unroll
        for (int rg = 0; rg < 4; ++rg)
            den[rg] += __shfl_xor(den[rg], off);

#pragma unroll
    for (int rg = 0; rg < 4; ++rg) {
        const float inv = 1.0f / den[rg];
        const int l = i0 + iiB + rg;
#pragma unroll
        for (int nt = 0; nt < 4; ++nt)
            ctx[((size_t)(b * L_ + l) << 10) + (h << 6) + (nt << 4) + fr] =
                f2bf(acc_o[nt][rg] * inv);
    }
}

// ---------------------------------------------------------------------------
extern "C" void kernel_launch(void* const* d_in, const int* in_sizes, int n_in,
                              void* d_out, int out_size, void* d_ws, size_t ws_size,
                              hipStream_t stream)
{
    const float* x   = (const float*)d_in[0];
    const float* Wq  = (const float*)d_in[1];
    const float* bq  = (const float*)d_in[2];
    const float* Wk  = (const float*)d_in[3];
    const float* bk  = (const float*)d_in[4];
    const float* Wv  = (const float*)d_in[5];
    const float* bv  = (const float*)d_in[6];
    const float* Wo  = (const float*)d_in[7];
    const float* bo  = (const float*)d_in[8];
    const float* rel = (const float*)d_in[9];
    float* out = (float*)d_out;

    short* xb     = (short*)d_ws;                       // 4096x1024 bf16
    short* qkv    = xb + (size_t)HEADSZ_;               // q plain, k image, v image
    short* cw     = qkv + (size_t)3 * HEADSZ_;          // ctx bf16 [B*L, HID]
    short* wt     = cw + (size_t)HEADSZ_;               // 4 x HID^2 bf16
    short* relimg = wt + (size_t)4 * HID_ * HID_;       // 32 x 4096 shorts

    const dim3 tb(256);

    prep_k<<<dim3(3136), tb, 0, stream>>>(x, Wq, Wk, Wv, Wo, rel, xb, wt, relimg);

    // fused QKV GEMM: N=3072, tile 128x128, BK=32
    gemm_glds_k<<<dim3(24, 32), tb, 0, stream>>>(
        xb, wt, bq, bk, bv, qkv, HID_, 1);

    attn_mfma_k<<<dim3(16, H_, B_), tb, 0, stream>>>(
        qkv, qkv + HEADSZ_, qkv + 2 * (size_t)HEADSZ_, relimg, cw);

    // output GEMM: N=1024, tile 128x128, BK=32
    gemm_glds_k<<<dim3(8, 32), tb, 0, stream>>>(
        cw, wt + (size_t)3 * HID_ * HID_, bo, bo, bo, out, HID_, 0);
}

// Round 9
// 218.759 us; speedup vs baseline: 1.0712x; 1.0712x over previous
//
#include <hip/hip_runtime.h>
#include <cstddef>

#define B_ 4
#define L_ 1024
#define H_ 16
#define DH_ 64
#define HID_ 1024
#define HEADSZ_ 4194304   // B*H*L*DH

typedef short bf16x8 __attribute__((ext_vector_type(8)));
typedef short bf16x4 __attribute__((ext_vector_type(4)));
typedef float f32x4  __attribute__((ext_vector_type(4)));

__device__ __forceinline__ short f2bf(float f) {
    unsigned u = __float_as_uint(f);
    u = (u + 0x7fffu + ((u >> 16) & 1u)) >> 16;   // RNE
    return (short)u;
}
__device__ __forceinline__ float bf2f(short s) {
    return __uint_as_float(((unsigned)(unsigned short)s) << 16);
}
__device__ __forceinline__ void glds16(const short* g, short* l) {
    __builtin_amdgcn_global_load_lds(
        (const __attribute__((address_space(1))) unsigned int*)g,
        (__attribute__((address_space(3))) unsigned int*)l, 16, 0, 0);
}

// ---------------------------------------------------------------------------
// Merged prep: [0,2048) xcast | [2048,3072) wcast4 | [3072,3136) relcast.
// ---------------------------------------------------------------------------
__global__ __launch_bounds__(256) void prep_k(
    const float* __restrict__ x,
    const float* __restrict__ Wq, const float* __restrict__ Wk,
    const float* __restrict__ Wv, const float* __restrict__ Wo,
    const float* __restrict__ rel,
    short* __restrict__ xb, short* __restrict__ Wt, short* __restrict__ relimg)
{
    const int bid = blockIdx.x;
    const int t   = threadIdx.x;
    if (bid < 2048) {                      // x fp32 -> bf16
        const int base = (bid * 256 + t) << 3;
        float4 f0 = *(const float4*)&x[base];
        float4 f1 = *(const float4*)&x[base + 4];
        bf16x8 p;
        p[0] = f2bf(f0.x); p[1] = f2bf(f0.y); p[2] = f2bf(f0.z); p[3] = f2bf(f0.w);
        p[4] = f2bf(f1.x); p[5] = f2bf(f1.y); p[6] = f2bf(f1.z); p[7] = f2bf(f1.w);
        *(bf16x8*)&xb[base] = p;
    } else if (bid < 3072) {               // W transpose+cast: Wt[n][k] = W[k][n]
        const int idx = bid - 2048;
        const int z = idx >> 8, tile = idx & 255;
        const float* W = (z == 0) ? Wq : (z == 1) ? Wk : (z == 2) ? Wv : Wo;
        short* dstb = Wt + (size_t)z * HID_ * HID_;
        __shared__ float T[64][65];
        const int k0 = (tile & 15) << 6, n0 = (tile >> 4) << 6;
        const int r  = t & 63;
        const int cg = t >> 6;
#pragma unroll
        for (int u = 0; u < 4; ++u) {
            float4 f = *(const float4*)&W[(size_t)(k0 + r) * HID_ + n0 + (cg << 4) + (u << 2)];
            T[r][(cg << 4) + (u << 2) + 0] = f.x;
            T[r][(cg << 4) + (u << 2) + 1] = f.y;
            T[r][(cg << 4) + (u << 2) + 2] = f.z;
            T[r][(cg << 4) + (u << 2) + 3] = f.w;
        }
        __syncthreads();
        bf16x8 p0, p1;
#pragma unroll
        for (int j = 0; j < 8; ++j) p0[j] = f2bf(T[(cg << 4) + j][r]);
#pragma unroll
        for (int j = 0; j < 8; ++j) p1[j] = f2bf(T[(cg << 4) + 8 + j][r]);
        short* dst = &dstb[(size_t)(n0 + r) * HID_ + k0 + (cg << 4)];
        *(bf16x8*)dst       = p0;
        *(bf16x8*)(dst + 8) = p1;
    } else {                               // rel -> 32 swizzled 8KB chunk images
        const int base = ((bid - 3072) * 256 + t) << 3;
        if (base >= 2047 * 64) return;
        const int r = base >> 6, d0 = base & 63;
        float4 f0 = *(const float4*)&rel[base];
        float4 f1 = *(const float4*)&rel[base + 4];
        bf16x8 p;
        p[0] = f2bf(f0.x); p[1] = f2bf(f0.y); p[2] = f2bf(f0.z); p[3] = f2bf(f0.w);
        p[4] = f2bf(f1.x); p[5] = f2bf(f1.y); p[6] = f2bf(f1.z); p[7] = f2bf(f1.w);
        const size_t dst = ((size_t)(r >> 6) << 12) + ((r & 63) << 6)
                         + ((((d0 >> 3) ^ (r & 7))) << 3);
        *(bf16x8*)&relimg[dst] = p;
    }
}

// ---------------------------------------------------------------------------
// bf16 MFMA GEMM, 128 x (NT*32) tile, BK=32, glds staging, source-permuted
// swizzle (slot g holds kgroup g^((row>>1)&3)). NT=4: 128-wide; NT=2: 64.
// mode 0: fp32 out (bias b0). mode 1: bf16 qkv (q plain / k image / v image).
// ---------------------------------------------------------------------------
template <int NT>
__global__ __launch_bounds__(256, 3) void gemm_glds_k(
    const short* __restrict__ A, const short* __restrict__ Wt,
    const float* __restrict__ b0, const float* __restrict__ b1,
    const float* __restrict__ b2, void* __restrict__ outv,
    int K, int mode)
{
    constexpr int BN = NT * 32;
    __shared__ short As[128 * 32];
    __shared__ short Bs[BN * 32];

    const int t    = threadIdx.x;
    const int lane = t & 63, w = t >> 6;
    const int m0   = blockIdx.y << 7, n0 = blockIdx.x * BN;
    const int fr   = lane & 15, qd = lane >> 4;
    const int wm0  = (w & 1) << 6, wn0 = (w >> 1) * (NT << 4);

    const int srow = lane >> 2;                      // 0..15 within 16-row chunk
    const int sg   = (lane & 3) ^ ((lane >> 3) & 3); // swizzled source kgroup
    const int slot = qd ^ ((fr >> 1) & 3);           // read-side slot group

    f32x4 acc[4][NT];
#pragma unroll
    for (int i = 0; i < 4; ++i)
#pragma unroll
        for (int j = 0; j < NT; ++j) acc[i][j] = (f32x4){0.f, 0.f, 0.f, 0.f};

    const short* aBase  = A  + (size_t)(m0 + w * 32 + srow) * K + sg * 8;
    const short* aBase2 = aBase + (size_t)16 * K;
    const short* bBase  = Wt + (size_t)(n0 + w * (BN / 4) + srow) * K + sg * 8;
    const short* bBase2 = bBase + (size_t)16 * K;
    short* aDst  = &As[(w * 32) * 32];
    short* aDst2 = &As[(w * 32 + 16) * 32];
    short* bDst  = &Bs[(w * (BN / 4)) * 32];
    short* bDst2 = &Bs[(w * (BN / 4) + 16) * 32];

    for (int k0 = 0; k0 < K; k0 += 32) {
        __syncthreads();
        glds16(aBase + k0, aDst);
        glds16(aBase2 + k0, aDst2);
        glds16(bBase + k0, bDst);
        if (NT == 4) glds16(bBase2 + k0, bDst2);
        __syncthreads();

        bf16x8 af[4], bfv[NT];
#pragma unroll
        for (int mt = 0; mt < 4; ++mt)
            af[mt] = *(const bf16x8*)&As[((wm0 + (mt << 4) + fr) << 5) + (slot << 3)];
#pragma unroll
        for (int nt = 0; nt < NT; ++nt)
            bfv[nt] = *(const bf16x8*)&Bs[((wn0 + (nt << 4) + fr) << 5) + (slot << 3)];
#pragma unroll
        for (int mt = 0; mt < 4; ++mt)
#pragma unroll
            for (int nt = 0; nt < NT; ++nt)
                acc[mt][nt] = __builtin_amdgcn_mfma_f32_16x16x32_bf16(
                    af[mt], bfv[nt], acc[mt][nt], 0, 0, 0);
    }

#pragma unroll
    for (int nt = 0; nt < NT; ++nt) {
        const int coln = n0 + wn0 + (nt << 4) + fr;
        float bias;
        if (mode == 0) bias = b0[coln];
        else {
            const int t3 = coln >> 10;
            bias = (t3 == 0 ? b0 : t3 == 1 ? b1 : b2)[coln & 1023];
        }
#pragma unroll
        for (int mt = 0; mt < 4; ++mt)
#pragma unroll
            for (int rg = 0; rg < 4; ++rg) {
                const int row = m0 + wm0 + (mt << 4) + (qd << 2) + rg;
                const float val = acc[mt][nt][rg] + bias;
                if (mode == 0) {
                    ((float*)outv)[(size_t)row * HID_ + coln] = val;
                } else {
                    const int t3 = coln >> 10;
                    const int h  = (coln >> 6) & 15;
                    const int d  = coln & 63;
                    const int bb = row >> 10, l = row & 1023;
                    const size_t bhoff = ((size_t)(bb * H_ + h)) << 16;
                    size_t dst;
                    if (t3 == 0)        // q: plain [b,h,l,d]
                        dst = bhoff + ((size_t)l << 6) + d;
                    else if (t3 == 1)   // k: swizzled tile image
                        dst = (size_t)HEADSZ_ + bhoff + ((size_t)(l >> 6) << 12)
                            + ((l & 63) << 6) + ((((d >> 3) ^ (l & 7))) << 3) + (d & 7);
                    else                // v: transposed swizzled tile image [d][j=l]
                        dst = 2 * (size_t)HEADSZ_ + bhoff + ((size_t)(l >> 6) << 12)
                            + ((size_t)d << 6) + (((((l >> 3) & 7) ^ (d & 7))) << 3) + (l & 7);
                    ((short*)outv)[dst] = f2bf(val);
                }
            }
    }
}

// ---------------------------------------------------------------------------
// MFMA attention, S^T/O^T formulation. Per block (b,h,64-row Q tile), 4 waves.
// S^T = mfma(K-frag, Q-frag): thread owns ONE row ii=w*16+fr, 16 jj values ->
// P stored with 4 aligned b64 writes (was 16 scalar), den is a scalar.
// O^T = mfma(Vt-frag, P-frag). K/V/rel staged via glds16 from pre-swizzled
// images (single-buffer: R8 showed dbuf's occupancy loss outweighs prefetch).
// Rolling bf16 T double-buffer (T[ii][c], wave-private). 51200 B -> 3 blk/CU.
// ---------------------------------------------------------------------------
__global__ __launch_bounds__(256, 3) void attn_mfma_k(
    const short* __restrict__ q, const short* __restrict__ kimg,
    const short* __restrict__ vimg, const short* __restrict__ relimg,
    short* __restrict__ ctx)
{
    __shared__ __align__(16) short Ks[64 * 64];
    __shared__ __align__(16) short Vt[64 * 64];
    __shared__ __align__(16) short Rl[64 * 64];
    __shared__ __align__(16) short Ts[2 * 64 * 68];   // [par][c][ii]
    __shared__ __align__(16) short Ps[64 * 72];       // [ii][jj] row-major

    const int t    = threadIdx.x;
    const int i0   = blockIdx.x << 6;
    const int h    = blockIdx.y;
    const int b    = blockIdx.z;
    const size_t bh = (size_t)(b * H_ + h) << 16;
    const int lane = t & 63, w = t >> 6;
    const int fr   = lane & 15, qd = lane >> 4;
    const int m16  = i0 >> 6;
    const int iiB  = (w << 4) + (qd << 2);   // T-producer col base
    const int ii   = (w << 4) + fr;          // this thread's S^T row
    const int soff = w * 1024 + lane * 8;

    // Q fragments (A-layout for T production, B-layout for S^T — same regs)
    bf16x8 af[2];
#pragma unroll
    for (int hh = 0; hh < 2; ++hh)
        af[hh] = *(const bf16x8*)&q[bh + ((size_t)(i0 + (w << 4) + fr) << 6)
                                    + (((hh << 2) + qd) << 3)];

    // prologue: rel chunk m16+16 -> T into parity m16&1
    glds16(relimg + ((size_t)(m16 + 16) << 12) + soff,       Rl + w * 1024);
    glds16(relimg + ((size_t)(m16 + 16) << 12) + soff + 512, Rl + w * 1024 + 512);
    __syncthreads();
    {
        f32x4 acc_t[4];
#pragma unroll
        for (int i = 0; i < 4; ++i) acc_t[i] = (f32x4){0.f, 0.f, 0.f, 0.f};
#pragma unroll
        for (int hh = 0; hh < 2; ++hh) {
            const int g = (hh << 2) + qd;
#pragma unroll
            for (int rt = 0; rt < 4; ++rt) {
                const int rr = (rt << 4) + fr;
                bf16x8 br = *(const bf16x8*)&Rl[(rr << 6) + ((g ^ (rr & 7)) << 3)];
                acc_t[rt] = __builtin_amdgcn_mfma_f32_16x16x32_bf16(af[hh], br, acc_t[rt], 0, 0, 0);
            }
        }
        const int pu = m16 & 1;
#pragma unroll
        for (int rt = 0; rt < 4; ++rt) {
            bf16x4 p;
            p[0] = f2bf(acc_t[rt][0]); p[1] = f2bf(acc_t[rt][1]);
            p[2] = f2bf(acc_t[rt][2]); p[3] = f2bf(acc_t[rt][3]);
            *(bf16x4*)&Ts[pu * 4352 + ((rt << 4) + fr) * 68 + iiB] = p;
        }
    }

    f32x4 acc_o[4];   // O^T: acc_o[mt][rg] = O[ii][d = mt*16+qd*4+rg]
#pragma unroll
    for (int i = 0; i < 4; ++i) acc_o[i] = (f32x4){0.f, 0.f, 0.f, 0.f};
    float den = 0.f;

    for (int jt = 0; jt < 16; ++jt) {
        const int mlow = m16 + 15 - jt;
        const int pl   = mlow & 1;

        __syncthreads();   // prev tile's reads complete
        glds16(kimg + bh + ((size_t)jt << 12) + soff,       Ks + w * 1024);
        glds16(kimg + bh + ((size_t)jt << 12) + soff + 512, Ks + w * 1024 + 512);
        glds16(vimg + bh + ((size_t)jt << 12) + soff,       Vt + w * 1024);
        glds16(vimg + bh + ((size_t)jt << 12) + soff + 512, Vt + w * 1024 + 512);
        glds16(relimg + ((size_t)mlow << 12) + soff,        Rl + w * 1024);
        glds16(relimg + ((size_t)mlow << 12) + soff + 512,  Rl + w * 1024 + 512);
        __syncthreads();   // staged tiles visible

        // S^T = K·Q^T : acc_s[mt] rows jj = mt*16+qd*4+rg, col ii = w*16+fr
        f32x4 acc_s[4];
#pragma unroll
        for (int i = 0; i < 4; ++i) acc_s[i] = (f32x4){0.f, 0.f, 0.f, 0.f};
#pragma unroll
        for (int hh = 0; hh < 2; ++hh) {
            const int g = (hh << 2) + qd;
#pragma unroll
            for (int mt = 0; mt < 4; ++mt) {
                const int rb = (mt << 4) + fr;
                bf16x8 bk = *(const bf16x8*)&Ks[(rb << 6) + ((g ^ (rb & 7)) << 3)];
                acc_s[mt] = __builtin_amdgcn_mfma_f32_16x16x32_bf16(bk, af[hh], acc_s[mt], 0, 0, 0);
            }
        }

        // new T chunk (rows 64*mlow..+63): T[ii][c] layout, unchanged producer
        {
            f32x4 acc_t[4];
#pragma unroll
            for (int i = 0; i < 4; ++i) acc_t[i] = (f32x4){0.f, 0.f, 0.f, 0.f};
#pragma unroll
            for (int hh = 0; hh < 2; ++hh) {
                const int g = (hh << 2) + qd;
#pragma unroll
                for (int rt = 0; rt < 4; ++rt) {
                    const int rr = (rt << 4) + fr;
                    bf16x8 br = *(const bf16x8*)&Rl[(rr << 6) + ((g ^ (rr & 7)) << 3)];
                    acc_t[rt] = __builtin_amdgcn_mfma_f32_16x16x32_bf16(af[hh], br, acc_t[rt], 0, 0, 0);
                }
            }
#pragma unroll
            for (int rt = 0; rt < 4; ++rt) {
                bf16x4 p;
                p[0] = f2bf(acc_t[rt][0]); p[1] = f2bf(acc_t[rt][1]);
                p[2] = f2bf(acc_t[rt][2]); p[3] = f2bf(acc_t[rt][3]);
                *(bf16x4*)&Ts[pl * 4352 + ((rt << 4) + fr) * 68 + iiB] = p;
            }
        }
        // Ts/Ps wave-private: intra-wave lgkm ordering suffices

        // exp + T gather + P row-store (4 aligned b64 writes)
#pragma unroll
        for (int mt = 0; mt < 4; ++mt) {
            bf16x4 pk;
#pragma unroll
            for (int rg = 0; rg < 4; ++rg) {
                const int jj = (mt << 4) + (qd << 2) + rg;
                const int c  = ii - jj + 63;                 // [0,126]
                const int par = pl ^ (c >> 6);
                const float tv = bf2f(Ts[par * 4352 + (c & 63) * 68 + ii]);
                float s = acc_s[mt][rg] * 0.125f;
                s = fminf(fmaxf(s, -100000.f), 100000.f);
                const float e = __expf(s + tv);
                den += e;
                pk[rg] = f2bf(e);
            }
            *(bf16x4*)&Ps[ii * 72 + (mt << 4) + (qd << 2)] = pk;
        }

        // O^T += V^T·P^T : a = Vt rows (d), b = Ps row ii (jj-contiguous)
#pragma unroll
        for (int hh = 0; hh < 2; ++hh) {
            const int g = (hh << 2) + qd;
            bf16x8 bp = *(const bf16x8*)&Ps[ii * 72 + (g << 3)];
#pragma unroll
            for (int mt = 0; mt < 4; ++mt) {
                const int rb = (mt << 4) + fr;
                bf16x8 av = *(const bf16x8*)&Vt[(rb << 6) + ((g ^ (rb & 7)) << 3)];
                acc_o[mt] = __builtin_amdgcn_mfma_f32_16x16x32_bf16(av, bp, acc_o[mt], 0, 0, 0);
            }
        }
    }

    // den: full row ii = sum over the 4 qd groups (lanes ^16, ^32)
    den += __shfl_xor(den, 16);
    den += __shfl_xor(den, 32);
    const float inv = 1.0f / den;

    const int l = i0 + ii;
#pragma unroll
    for (int mt = 0; mt < 4; ++mt) {
        bf16x4 o;
#pragma unroll
        for (int rg = 0; rg < 4; ++rg) o[rg] = f2bf(acc_o[mt][rg] * inv);
        *(bf16x4*)&ctx[((size_t)(b * L_ + l) << 10) + (h << 6) + (mt << 4) + (qd << 2)] = o;
    }
}

// ---------------------------------------------------------------------------
extern "C" void kernel_launch(void* const* d_in, const int* in_sizes, int n_in,
                              void* d_out, int out_size, void* d_ws, size_t ws_size,
                              hipStream_t stream)
{
    const float* x   = (const float*)d_in[0];
    const float* Wq  = (const float*)d_in[1];
    const float* bq  = (const float*)d_in[2];
    const float* Wk  = (const float*)d_in[3];
    const float* bk  = (const float*)d_in[4];
    const float* Wv  = (const float*)d_in[5];
    const float* bv  = (const float*)d_in[6];
    const float* Wo  = (const float*)d_in[7];
    const float* bo  = (const float*)d_in[8];
    const float* rel = (const float*)d_in[9];
    float* out = (float*)d_out;

    short* xb     = (short*)d_ws;                       // 4096x1024 bf16
    short* qkv    = xb + (size_t)HEADSZ_;               // q plain, k image, v image
    short* cw     = qkv + (size_t)3 * HEADSZ_;          // ctx bf16 [B*L, HID]
    short* wt     = cw + (size_t)HEADSZ_;               // 4 x HID^2 bf16
    short* relimg = wt + (size_t)4 * HID_ * HID_;       // 32 x 4096 shorts

    const dim3 tb(256);

    prep_k<<<dim3(3136), tb, 0, stream>>>(x, Wq, Wk, Wv, Wo, rel, xb, wt, relimg);

    // fused QKV GEMM: N=3072, tile 128x128, BK=32
    gemm_glds_k<4><<<dim3(24, 32), tb, 0, stream>>>(
        xb, wt, bq, bk, bv, qkv, HID_, 1);

    attn_mfma_k<<<dim3(16, H_, B_), tb, 0, stream>>>(
        qkv, qkv + HEADSZ_, qkv + 2 * (size_t)HEADSZ_, relimg, cw);

    // output GEMM: N=1024, tile 128x64 -> 512 blocks (2/CU)
    gemm_glds_k<2><<<dim3(16, 32), tb, 0, stream>>>(
        cw, wt + (size_t)3 * HID_ * HID_, bo, bo, bo, out, HID_, 0);
}